// Round 8
// baseline (161.519 us; speedup 1.0000x reference)
//
#include <hip/hip_runtime.h>
#include <hip/hip_bf16.h>

typedef __attribute__((ext_vector_type(8))) short short8;
typedef __attribute__((ext_vector_type(4))) float f32x4;

static constexpr int IN = 32, OUT = 32, DYNDIM = 16, KNBR = 7;
static constexpr int ROWS = 320;              // rows per block (10 waves x 32)
static constexpr int PAD  = 192;              // max |nbr - n| = 191 < 192
static constexpr int WIN  = ROWS + 2 * PAD;   // 704-row staged window
static constexpr int LROW = 36;               // shorts per LDS row (32 + 4 pad)
static constexpr int NT   = 640;              // threads per block (10 waves)

__device__ inline unsigned short f2bf(float f) {
    unsigned u = __builtin_bit_cast(unsigned, f);
    unsigned r = (u + 0x7fffu + ((u >> 16) & 1u)) >> 16;   // RNE
    return (unsigned short)r;
}

// ---------- Kernel 1: combined weights, bf16, B-fragment layout ----------
// Wp[b][k][ch][lane][j], lane=(i>>3)*16+(o&15), j=i&7
__global__ void pack_weights(const float* __restrict__ dyn,
                             const float* __restrict__ Wdyn,
                             const float* __restrict__ Wstat,
                             unsigned short* __restrict__ Wp)
{
    int bk = blockIdx.x;              // b*7 + k
    int k  = bk % KNBR;
    __shared__ float dsh[DYNDIM];
    if (threadIdx.x < DYNDIM)
        dsh[threadIdx.x] = dyn[(size_t)bk * DYNDIM + threadIdx.x];
    __syncthreads();

    for (int e = threadIdx.x; e < IN * OUT; e += blockDim.x) {
        int i = e >> 5, o = e & 31;
        float acc = Wstat[((size_t)k * IN + i) * OUT + o];
        const float* wd = Wdyn + (((size_t)k * DYNDIM) * IN + i) * OUT + o;
#pragma unroll
        for (int d = 0; d < DYNDIM; ++d)
            acc += dsh[d] * wd[(size_t)d * IN * OUT];
        int ch = o >> 4, cc = o & 15, g = i >> 3, j = i & 7;
        Wp[(((size_t)bk * 2 + ch) * 64 + (g * 16 + cc)) * 8 + j] = f2bf(acc);
    }
}

// ---------- Kernel 2 (fused main) ----------
// f32 window -> LDS bf16; B-fragments in registers; idx software-pipelined;
// XCD-chunked swizzle. 640 threads, 320 rows/block, 3 blocks/CU = 30 waves/CU.
__global__ __launch_bounds__(NT, 8) void hexconv_fused(
    const float* __restrict__ grid,        // (B,N,32) f32
    const int* __restrict__ nbr,           // (7,N)
    const unsigned short* __restrict__ Wp, // (B,7,2,64,8) bf16
    const float* __restrict__ bias,        // (32)
    float* __restrict__ out,               // (B,N,32) f32
    int N)
{
    __shared__ unsigned short glds[WIN * LROW];   // 50688 B

    // XCD-chunked bijective remap (nwg % 8 == 0 for the real shape)
    const int nwgx = gridDim.x;
    const int nwg  = nwgx * gridDim.y;
    int orig = blockIdx.x + nwgx * blockIdx.y;
    int wg = orig;
    if ((nwg & 7) == 0) {
        int cpx = nwg >> 3;
        wg = (orig & 7) * cpx + (orig >> 3);
    }
    const int bx = wg % nwgx;
    const int b  = wg / nwgx;

    const int base   = bx * ROWS;
    const int win_lo = base - PAD;
    const size_t gbase = (size_t)b * N * 32;

    const int lane = threadIdx.x & 63;
    const int w    = threadIdx.x >> 6;          // wave 0..9
    const int g    = lane >> 4;
    const int c    = lane & 15;
    const int wbase = base + w * 32;            // 32 rows per wave = 2 subtiles

    // B fragments -> registers (issued first; complete under staging)
    const unsigned short* wpb = Wp + (size_t)b * KNBR * 1024;
    short8 bw[KNBR][2];
#pragma unroll
    for (int kk = 0; kk < KNBR; ++kk)
#pragma unroll
        for (int ch = 0; ch < 2; ++ch)
            bw[kk][ch] = *(const short8*)(wpb + ((size_t)(kk * 2 + ch) * 64 + lane) * 8);

    // t=0 neighbor indices, issued before staging (hidden under it)
    int idxc[KNBR];
    {
        const int n0 = wbase + c;
        const bool v = (n0 < N);
#pragma unroll
        for (int kk = 0; kk < KNBR; ++kk) {
            if (kk == 3) idxc[kk] = v ? n0 : -1;         // center: nbr[3,n] == n
            else         idxc[kk] = v ? nbr[(size_t)kk * N + n0] : -1;
        }
    }

    // stage grid window: coalesced f32 reads, cvt, padded LDS bf16 rows
    for (int e = threadIdx.x; e < WIN * 4; e += NT) {
        int row = e >> 2, seg = e & 3;
        int gr = win_lo + row;
        if (gr >= 0 && gr < N) {
            const float* gp = grid + gbase + (size_t)gr * 32 + seg * 8;
            float4 x0 = *(const float4*)gp;
            float4 x1 = *(const float4*)(gp + 4);
            short8 vv;
            vv[0] = (short)f2bf(x0.x); vv[1] = (short)f2bf(x0.y);
            vv[2] = (short)f2bf(x0.z); vv[3] = (short)f2bf(x0.w);
            vv[4] = (short)f2bf(x1.x); vv[5] = (short)f2bf(x1.y);
            vv[6] = (short)f2bf(x1.z); vv[7] = (short)f2bf(x1.w);
            *(short8*)(glds + row * LROW + seg * 8) = vv;
        }
    }
    __syncthreads();

    const float bc0 = bias[c];
    const float bc1 = bias[16 + c];

#pragma unroll
    for (int t = 0; t < 2; ++t) {
        // prefetch next sub-tile's indices before this tile's MFMA cluster
        int idxn[KNBR];
        if (t < 1) {
            const int n1 = wbase + 16 + c;
            const bool v = (n1 < N);
#pragma unroll
            for (int kk = 0; kk < KNBR; ++kk) {
                if (kk == 3) idxn[kk] = v ? n1 : -1;
                else         idxn[kk] = v ? nbr[(size_t)kk * N + n1] : -1;
            }
        }

        f32x4 acc0 = {0.f, 0.f, 0.f, 0.f};
        f32x4 acc1 = {0.f, 0.f, 0.f, 0.f};
#pragma unroll
        for (int kk = 0; kk < KNBR; ++kk) {
            short8 a = {0, 0, 0, 0, 0, 0, 0, 0};
            int id = idxc[kk];
            if (id >= 0)
                a = *(const short8*)(glds + (size_t)(id - win_lo) * LROW + g * 8);
            acc0 = __builtin_amdgcn_mfma_f32_16x16x32_bf16(a, bw[kk][0], acc0, 0, 0, 0);
            acc1 = __builtin_amdgcn_mfma_f32_16x16x32_bf16(a, bw[kk][1], acc1, 0, 0, 0);
        }

        const int row_base = wbase + t * 16 + g * 4;
#pragma unroll
        for (int r = 0; r < 4; ++r) {
            int row = row_base + r;
            if (row < N) {
                float* op = out + gbase + (size_t)row * 32;
                op[c]      = acc0[r] + bc0;
                op[16 + c] = acc1[r] + bc1;
            }
        }

        if (t < 1) {
#pragma unroll
            for (int kk = 0; kk < KNBR; ++kk) idxc[kk] = idxn[kk];
        }
    }
}

extern "C" void kernel_launch(void* const* d_in, const int* in_sizes, int n_in,
                              void* d_out, int out_size, void* d_ws, size_t ws_size,
                              hipStream_t stream)
{
    const float* grid  = (const float*)d_in[0];
    const float* dyn   = (const float*)d_in[1];
    const int*   nbr   = (const int*)d_in[2];
    const float* Wdyn  = (const float*)d_in[3];
    const float* Wstat = (const float*)d_in[4];
    const float* bias  = (const float*)d_in[5];
    float* out = (float*)d_out;

    const int N = in_sizes[2] / KNBR;               // 27361
    const int B = in_sizes[0] / (N * IN);           // 32

    unsigned short* Wp = (unsigned short*)d_ws;     // B*7*1024 bf16 = 458752 B
    pack_weights<<<B * KNBR, 256, 0, stream>>>(dyn, Wdyn, Wstat, Wp);

    dim3 grd((N + ROWS - 1) / ROWS, B);
    hexconv_fused<<<grd, NT, 0, stream>>>(grid, nbr, Wp, bias, out, N);
}

// Round 9
// 53.736 us; speedup vs baseline: 3.0058x; 3.0058x over previous
//
#include <hip/hip_runtime.h>
#include <hip/hip_bf16.h>

typedef __attribute__((ext_vector_type(8))) short short8;
typedef __attribute__((ext_vector_type(4))) float f32x4;

static constexpr int IN = 32, OUT = 32, DYNDIM = 16, KNBR = 7;
static constexpr int ROWS = 512;              // rows per block
static constexpr int PAD  = 192;              // max |nbr - n| = 191 < 192
static constexpr int WIN  = ROWS + 2 * PAD;   // 896-row staged window
static constexpr int LROW = 36;               // shorts per LDS row (32 + 4 pad)
static constexpr int NT   = 512;              // threads per block (8 waves)

__device__ inline unsigned short f2bf(float f) {
    unsigned u = __builtin_bit_cast(unsigned, f);
    unsigned r = (u + 0x7fffu + ((u >> 16) & 1u)) >> 16;   // RNE
    return (unsigned short)r;
}

// ---------- Kernel 1: combined weights, bf16, B-fragment layout ----------
// Wp[b][k][ch][lane][j], lane=(i>>3)*16+(o&15), j=i&7
__global__ void pack_weights(const float* __restrict__ dyn,
                             const float* __restrict__ Wdyn,
                             const float* __restrict__ Wstat,
                             unsigned short* __restrict__ Wp)
{
    int bk = blockIdx.x;              // b*7 + k
    int k  = bk % KNBR;
    __shared__ float dsh[DYNDIM];
    if (threadIdx.x < DYNDIM)
        dsh[threadIdx.x] = dyn[(size_t)bk * DYNDIM + threadIdx.x];
    __syncthreads();

    for (int e = threadIdx.x; e < IN * OUT; e += blockDim.x) {
        int i = e >> 5, o = e & 31;
        float acc = Wstat[((size_t)k * IN + i) * OUT + o];
        const float* wd = Wdyn + (((size_t)k * DYNDIM) * IN + i) * OUT + o;
#pragma unroll
        for (int d = 0; d < DYNDIM; ++d)
            acc += dsh[d] * wd[(size_t)d * IN * OUT];
        int ch = o >> 4, cc = o & 15, g = i >> 3, j = i & 7;
        Wp[(((size_t)bk * 2 + ch) * 64 + (g * 16 + cc)) * 8 + j] = f2bf(acc);
    }
}

// ---------- Kernel 2 (fused main) ----------
// R6 structure: f32 window -> LDS bf16; B-fragments in registers; idx
// software-pipelined; XCD-chunked swizzle; 512 threads, 2 blocks/CU.
// NEW (R9): nontemporal output stores — keep grid slice L2-resident.
__global__ __launch_bounds__(NT, 4) void hexconv_fused(
    const float* __restrict__ grid,        // (B,N,32) f32
    const int* __restrict__ nbr,           // (7,N)
    const unsigned short* __restrict__ Wp, // (B,7,2,64,8) bf16
    const float* __restrict__ bias,        // (32)
    float* __restrict__ out,               // (B,N,32) f32
    int N)
{
    __shared__ unsigned short glds[WIN * LROW];   // 64512 B

    // XCD-chunked bijective remap (nwg % 8 == 0 for the real shape)
    const int nwgx = gridDim.x;
    const int nwg  = nwgx * gridDim.y;
    int orig = blockIdx.x + nwgx * blockIdx.y;
    int wg = orig;
    if ((nwg & 7) == 0) {
        int cpx = nwg >> 3;
        wg = (orig & 7) * cpx + (orig >> 3);
    }
    const int bx = wg % nwgx;
    const int b  = wg / nwgx;

    const int base   = bx * ROWS;
    const int win_lo = base - PAD;
    const size_t gbase = (size_t)b * N * 32;

    const int lane = threadIdx.x & 63;
    const int w    = threadIdx.x >> 6;          // wave 0..7
    const int g    = lane >> 4;
    const int c    = lane & 15;
    const int wbase = base + w * 64;            // 64 rows per wave

    // B fragments -> registers (issued first; complete under staging)
    const unsigned short* wpb = Wp + (size_t)b * KNBR * 1024;
    short8 bw[KNBR][2];
#pragma unroll
    for (int kk = 0; kk < KNBR; ++kk)
#pragma unroll
        for (int ch = 0; ch < 2; ++ch)
            bw[kk][ch] = *(const short8*)(wpb + ((size_t)(kk * 2 + ch) * 64 + lane) * 8);

    // t=0 neighbor indices, issued before staging (hidden under it)
    int idxc[KNBR];
    {
        const int n0 = wbase + c;
        const bool v = (n0 < N);
#pragma unroll
        for (int kk = 0; kk < KNBR; ++kk) {
            if (kk == 3) idxc[kk] = v ? n0 : -1;         // center: nbr[3,n] == n
            else         idxc[kk] = v ? nbr[(size_t)kk * N + n0] : -1;
        }
    }

    // stage grid window: coalesced f32 reads, cvt, padded LDS bf16 rows
    for (int e = threadIdx.x; e < WIN * 4; e += NT) {
        int row = e >> 2, seg = e & 3;
        int gr = win_lo + row;
        if (gr >= 0 && gr < N) {
            const float* gp = grid + gbase + (size_t)gr * 32 + seg * 8;
            float4 x0 = *(const float4*)gp;
            float4 x1 = *(const float4*)(gp + 4);
            short8 vv;
            vv[0] = (short)f2bf(x0.x); vv[1] = (short)f2bf(x0.y);
            vv[2] = (short)f2bf(x0.z); vv[3] = (short)f2bf(x0.w);
            vv[4] = (short)f2bf(x1.x); vv[5] = (short)f2bf(x1.y);
            vv[6] = (short)f2bf(x1.z); vv[7] = (short)f2bf(x1.w);
            *(short8*)(glds + row * LROW + seg * 8) = vv;
        }
    }
    __syncthreads();

    const float bc0 = bias[c];
    const float bc1 = bias[16 + c];

#pragma unroll
    for (int t = 0; t < 4; ++t) {
        // prefetch next sub-tile's indices before this tile's MFMA cluster
        int idxn[KNBR];
        if (t < 3) {
            const int n1 = wbase + (t + 1) * 16 + c;
            const bool v = (n1 < N);
#pragma unroll
            for (int kk = 0; kk < KNBR; ++kk) {
                if (kk == 3) idxn[kk] = v ? n1 : -1;
                else         idxn[kk] = v ? nbr[(size_t)kk * N + n1] : -1;
            }
        }

        f32x4 acc0 = {0.f, 0.f, 0.f, 0.f};
        f32x4 acc1 = {0.f, 0.f, 0.f, 0.f};
#pragma unroll
        for (int kk = 0; kk < KNBR; ++kk) {
            short8 a = {0, 0, 0, 0, 0, 0, 0, 0};
            int id = idxc[kk];
            if (id >= 0)
                a = *(const short8*)(glds + (size_t)(id - win_lo) * LROW + g * 8);
            acc0 = __builtin_amdgcn_mfma_f32_16x16x32_bf16(a, bw[kk][0], acc0, 0, 0, 0);
            acc1 = __builtin_amdgcn_mfma_f32_16x16x32_bf16(a, bw[kk][1], acc1, 0, 0, 0);
        }

        const int row_base = wbase + t * 16 + g * 4;
#pragma unroll
        for (int r = 0; r < 4; ++r) {
            int row = row_base + r;
            if (row < N) {
                float* op = out + gbase + (size_t)row * 32;
                __builtin_nontemporal_store(acc0[r] + bc0, op + c);
                __builtin_nontemporal_store(acc1[r] + bc1, op + 16 + c);
            }
        }

        if (t < 3) {
#pragma unroll
            for (int kk = 0; kk < KNBR; ++kk) idxc[kk] = idxn[kk];
        }
    }
}

extern "C" void kernel_launch(void* const* d_in, const int* in_sizes, int n_in,
                              void* d_out, int out_size, void* d_ws, size_t ws_size,
                              hipStream_t stream)
{
    const float* grid  = (const float*)d_in[0];
    const float* dyn   = (const float*)d_in[1];
    const int*   nbr   = (const int*)d_in[2];
    const float* Wdyn  = (const float*)d_in[3];
    const float* Wstat = (const float*)d_in[4];
    const float* bias  = (const float*)d_in[5];
    float* out = (float*)d_out;

    const int N = in_sizes[2] / KNBR;               // 27361
    const int B = in_sizes[0] / (N * IN);           // 32

    unsigned short* Wp = (unsigned short*)d_ws;     // B*7*1024 bf16 = 458752 B
    pack_weights<<<B * KNBR, 256, 0, stream>>>(dyn, Wdyn, Wstat, Wp);

    dim3 grd((N + ROWS - 1) / ROWS, B);
    hexconv_fused<<<grd, NT, 0, stream>>>(grid, nbr, Wp, bias, out, N);
}